// Round 1
// baseline (1619.458 us; speedup 1.0000x reference)
//
#include <hip/hip_runtime.h>
#include <hip/hip_bf16.h>

// Problem constants
#define T_TOK 2048
#define HID   1024
#define EXP   64
#define TOPK  8
#define IMED  512
#define GRP   128

// AWQ nibble shift order for flat column j within an int32 (8 nibbles)
__constant__ int kShifts[8] = {0, 16, 4, 20, 8, 24, 12, 28};

// ---------------- Routing: logits -> softmax -> top8 -> renorm -> expert lists ----------------
__global__ __launch_bounds__(64) void routing_kernel(
    const float* __restrict__ x, const float* __restrict__ gate_w,
    int* __restrict__ counts, int* __restrict__ tok_list,
    int* __restrict__ hslot_list, float* __restrict__ cw_list) {
  const int t = blockIdx.x;
  const int e = threadIdx.x;  // 64 lanes = 64 experts

  const float4* xv = reinterpret_cast<const float4*>(x + (size_t)t * HID);
  const float4* gv = reinterpret_cast<const float4*>(gate_w + (size_t)e * HID);
  float acc = 0.f;
#pragma unroll 8
  for (int i = 0; i < HID / 4; ++i) {
    float4 a = xv[i], b = gv[i];
    acc = fmaf(a.x, b.x, acc);
    acc = fmaf(a.y, b.y, acc);
    acc = fmaf(a.z, b.z, acc);
    acc = fmaf(a.w, b.w, acc);
  }

  // wave softmax over 64 experts
  float m = acc;
  for (int off = 32; off; off >>= 1) m = fmaxf(m, __shfl_xor(m, off));
  float p = expf(acc - m);
  float s = p;
  for (int off = 32; off; off >>= 1) s += __shfl_xor(s, off);
  float prob = p / s;

  // iterative top-8 via wave argmax (tie-break: lower index, matches lax.top_k)
  float pcur = prob;
  float myv = 0.f;
  int myi = -1;
  float tsum = 0.f;
  for (int k = 0; k < TOPK; ++k) {
    float v = pcur;
    int idx = e;
    for (int off = 32; off; off >>= 1) {
      float ov = __shfl_xor(v, off);
      int oi = __shfl_xor(idx, off);
      if (ov > v || (ov == v && oi < idx)) { v = ov; idx = oi; }
    }
    tsum += v;
    if (e == k) { myv = v; myi = idx; }
    if (e == idx) pcur = -1.f;  // remove winner
  }

  if (e < TOPK) {
    float cw = myv / tsum;
    int ex = myi;
    int slot = atomicAdd(&counts[ex], 1);
    tok_list[ex * T_TOK + slot] = t;
    hslot_list[ex * T_TOK + slot] = t * TOPK + e;  // row in h_buf
    cw_list[ex * T_TOK + slot] = cw;
  }
}

// ---------------- GEMM1: h[slot, i] = silu(x[t,:] . w1[e,i,:]) * cw ----------------
// w1[e,i,h] = dq1[h, e*512 + i]; qweight1 (1024 x 4096) int32, row-major.
#define BM 128
#define BN 128
#define BK 32
#define LDP (BM + 4)  // padded row stride (floats), multiple of 4 for aligned float4

__global__ __launch_bounds__(256) void gemm1_kernel(
    const float* __restrict__ x, const int* __restrict__ qw1,
    const int* __restrict__ qz1, const float* __restrict__ sc1,
    const int* __restrict__ counts, const int* __restrict__ tok_list,
    const int* __restrict__ hslot_list, const float* __restrict__ cw_list,
    float* __restrict__ h_buf) {
  const int e = blockIdx.z;
  const int n_e = counts[e];
  const int t0 = blockIdx.y * BM;
  if (t0 >= n_e) return;
  const int i_tile = blockIdx.x;  // 0..3, 128 i-cols each
  const int tid = threadIdx.x;

  __shared__ float As[BK][LDP];  // [k][token]
  __shared__ float Ws[BK][LDP];  // [k][i]

  // A loader mapping: row = tid/2 (0..127), 16 consecutive k per thread
  const int ar = tid >> 1;
  const int ac0 = (tid & 1) * 16;
  int atok = -1;
  if (t0 + ar < n_e) atok = tok_list[e * T_TOK + t0 + ar];

  const int tx = tid & 15;  // token dim
  const int ty = tid >> 4;  // i dim
  const int r0 = tx * 8;
  const int i0 = ty * 8;

  float acc[8][8];
#pragma unroll
  for (int a = 0; a < 8; ++a)
#pragma unroll
    for (int b = 0; b < 8; ++b) acc[a][b] = 0.f;

  for (int k0 = 0; k0 < HID; k0 += BK) {
    // ---- stage A (gathered x rows), transposed into [k][token] ----
    {
      float av[16];
      if (atok >= 0) {
        const float* src = x + (size_t)atok * HID + k0 + ac0;
        float4 v0 = *reinterpret_cast<const float4*>(src);
        float4 v1 = *reinterpret_cast<const float4*>(src + 4);
        float4 v2 = *reinterpret_cast<const float4*>(src + 8);
        float4 v3 = *reinterpret_cast<const float4*>(src + 12);
        av[0]=v0.x; av[1]=v0.y; av[2]=v0.z; av[3]=v0.w;
        av[4]=v1.x; av[5]=v1.y; av[6]=v1.z; av[7]=v1.w;
        av[8]=v2.x; av[9]=v2.y; av[10]=v2.z; av[11]=v2.w;
        av[12]=v3.x; av[13]=v3.y; av[14]=v3.z; av[15]=v3.w;
      } else {
#pragma unroll
        for (int j = 0; j < 16; ++j) av[j] = 0.f;
      }
#pragma unroll
      for (int j = 0; j < 16; ++j) As[ac0 + j][ar] = av[j];
    }
    // ---- dequant W tile into [k][i]: 32 k x 16 octets = 512 tasks ----
#pragma unroll
    for (int tsk = tid; tsk < 512; tsk += 256) {
      const int oct = tsk & 15;
      const int hh = tsk >> 4;  // 0..31
      const int row = k0 + hh;
      const int col = e * (IMED / 8) + i_tile * 16 + oct;  // 64 cols/expert
      const unsigned q = (unsigned)qw1[(size_t)row * 4096 + col];
      const int g = row >> 7;
      const unsigned z = (unsigned)qz1[(size_t)g * 4096 + col];
      const float* sp = sc1 + (size_t)g * 32768 + (size_t)col * 8;
      float4 s0 = *reinterpret_cast<const float4*>(sp);
      float4 s1 = *reinterpret_cast<const float4*>(sp + 4);
      float sv[8] = {s0.x, s0.y, s0.z, s0.w, s1.x, s1.y, s1.z, s1.w};
#pragma unroll
      for (int j = 0; j < 8; ++j) {
        int sh = kShifts[j];
        float val = (float)((int)((q >> sh) & 15u) - (int)((z >> sh) & 15u));
        Ws[hh][oct * 8 + j] = val * sv[j];
      }
    }
    __syncthreads();
    // ---- compute 8x8 microtile ----
#pragma unroll
    for (int c = 0; c < BK; ++c) {
      float4 a0 = *reinterpret_cast<const float4*>(&As[c][r0]);
      float4 a1 = *reinterpret_cast<const float4*>(&As[c][r0 + 4]);
      float4 b0 = *reinterpret_cast<const float4*>(&Ws[c][i0]);
      float4 b1 = *reinterpret_cast<const float4*>(&Ws[c][i0 + 4]);
      float av[8] = {a0.x, a0.y, a0.z, a0.w, a1.x, a1.y, a1.z, a1.w};
      float bv[8] = {b0.x, b0.y, b0.z, b0.w, b1.x, b1.y, b1.z, b1.w};
#pragma unroll
      for (int a = 0; a < 8; ++a)
#pragma unroll
        for (int b = 0; b < 8; ++b) acc[a][b] = fmaf(av[a], bv[b], acc[a][b]);
    }
    __syncthreads();
  }

  // ---- epilogue: silu * cw -> h_buf[hslot, i] ----
#pragma unroll
  for (int a = 0; a < 8; ++a) {
    const int r = t0 + r0 + a;
    if (r < n_e) {
      const float cw = cw_list[e * T_TOK + r];
      const int hs = hslot_list[e * T_TOK + r];
      float* dst = h_buf + (size_t)hs * IMED + i_tile * BN + i0;
      float o[8];
#pragma unroll
      for (int b = 0; b < 8; ++b) {
        float v = acc[a][b];
        o[b] = (v / (1.f + expf(-v))) * cw;
      }
      *reinterpret_cast<float4*>(dst) = make_float4(o[0], o[1], o[2], o[3]);
      *reinterpret_cast<float4*>(dst + 4) = make_float4(o[4], o[5], o[6], o[7]);
    }
  }
}

// ---------------- GEMM2: out[t, n] += h[slot,:] . w2[e,n,:] ----------------
// w2[e,n,i] = dq2[i, e*1024 + n]; qweight2 (512 x 8192) int32.
__global__ __launch_bounds__(256) void gemm2_kernel(
    const float* __restrict__ h_buf, const int* __restrict__ qw2,
    const int* __restrict__ qz2, const float* __restrict__ sc2,
    const int* __restrict__ counts, const int* __restrict__ tok_list,
    const int* __restrict__ hslot_list, float* __restrict__ out) {
  const int e = blockIdx.z;
  const int n_e = counts[e];
  const int t0 = blockIdx.y * BM;
  if (t0 >= n_e) return;
  const int n_tile = blockIdx.x;  // 0..7, 128 out-cols each
  const int tid = threadIdx.x;

  __shared__ float As[BK][LDP];
  __shared__ float Ws[BK][LDP];

  const int ar = tid >> 1;
  const int ac0 = (tid & 1) * 16;
  int ahs = -1;
  if (t0 + ar < n_e) ahs = hslot_list[e * T_TOK + t0 + ar];

  const int tx = tid & 15;
  const int ty = tid >> 4;
  const int r0 = tx * 8;
  const int n0 = ty * 8;

  float acc[8][8];
#pragma unroll
  for (int a = 0; a < 8; ++a)
#pragma unroll
    for (int b = 0; b < 8; ++b) acc[a][b] = 0.f;

  for (int k0 = 0; k0 < IMED; k0 += BK) {
    {
      float av[16];
      if (ahs >= 0) {
        const float* src = h_buf + (size_t)ahs * IMED + k0 + ac0;
        float4 v0 = *reinterpret_cast<const float4*>(src);
        float4 v1 = *reinterpret_cast<const float4*>(src + 4);
        float4 v2 = *reinterpret_cast<const float4*>(src + 8);
        float4 v3 = *reinterpret_cast<const float4*>(src + 12);
        av[0]=v0.x; av[1]=v0.y; av[2]=v0.z; av[3]=v0.w;
        av[4]=v1.x; av[5]=v1.y; av[6]=v1.z; av[7]=v1.w;
        av[8]=v2.x; av[9]=v2.y; av[10]=v2.z; av[11]=v2.w;
        av[12]=v3.x; av[13]=v3.y; av[14]=v3.z; av[15]=v3.w;
      } else {
#pragma unroll
        for (int j = 0; j < 16; ++j) av[j] = 0.f;
      }
#pragma unroll
      for (int j = 0; j < 16; ++j) As[ac0 + j][ar] = av[j];
    }
#pragma unroll
    for (int tsk = tid; tsk < 512; tsk += 256) {
      const int oct = tsk & 15;
      const int hh = tsk >> 4;
      const int row = k0 + hh;  // i index, 0..511
      const int col = e * (HID / 8) + n_tile * 16 + oct;  // 128 cols/expert
      const unsigned q = (unsigned)qw2[(size_t)row * 8192 + col];
      const int g = row >> 7;  // 0..3
      const unsigned z = (unsigned)qz2[(size_t)g * 8192 + col];
      const float* sp = sc2 + (size_t)g * 65536 + (size_t)col * 8;
      float4 s0 = *reinterpret_cast<const float4*>(sp);
      float4 s1 = *reinterpret_cast<const float4*>(sp + 4);
      float sv[8] = {s0.x, s0.y, s0.z, s0.w, s1.x, s1.y, s1.z, s1.w};
#pragma unroll
      for (int j = 0; j < 8; ++j) {
        int sh = kShifts[j];
        float val = (float)((int)((q >> sh) & 15u) - (int)((z >> sh) & 15u));
        Ws[hh][oct * 8 + j] = val * sv[j];
      }
    }
    __syncthreads();
#pragma unroll
    for (int c = 0; c < BK; ++c) {
      float4 a0 = *reinterpret_cast<const float4*>(&As[c][r0]);
      float4 a1 = *reinterpret_cast<const float4*>(&As[c][r0 + 4]);
      float4 b0 = *reinterpret_cast<const float4*>(&Ws[c][n0]);
      float4 b1 = *reinterpret_cast<const float4*>(&Ws[c][n0 + 4]);
      float av[8] = {a0.x, a0.y, a0.z, a0.w, a1.x, a1.y, a1.z, a1.w};
      float bv[8] = {b0.x, b0.y, b0.z, b0.w, b1.x, b1.y, b1.z, b1.w};
#pragma unroll
      for (int a = 0; a < 8; ++a)
#pragma unroll
        for (int b = 0; b < 8; ++b) acc[a][b] = fmaf(av[a], bv[b], acc[a][b]);
    }
    __syncthreads();
  }

#pragma unroll
  for (int a = 0; a < 8; ++a) {
    const int r = t0 + r0 + a;
    if (r < n_e) {
      const int t = tok_list[e * T_TOK + r];
      float* dst = out + (size_t)t * HID + n_tile * BN + n0;
#pragma unroll
      for (int b = 0; b < 8; ++b) atomicAdd(dst + b, acc[a][b]);
    }
  }
}

extern "C" void kernel_launch(void* const* d_in, const int* in_sizes, int n_in,
                              void* d_out, int out_size, void* d_ws, size_t ws_size,
                              hipStream_t stream) {
  const float* x      = (const float*)d_in[0];
  const float* gate_w = (const float*)d_in[1];
  const int*   qw1    = (const int*)d_in[2];
  const int*   qz1    = (const int*)d_in[3];
  const float* sc1    = (const float*)d_in[4];
  const int*   qw2    = (const int*)d_in[5];
  const int*   qz2    = (const int*)d_in[6];
  const float* sc2    = (const float*)d_in[7];
  float* out = (float*)d_out;

  // workspace layout (bytes):
  // counts:      [0, 256)
  // tok_list:    [256, 256+512K)
  // hslot_list:  next 512K
  // cw_list:     next 512K
  // h_buf:       next 33.5MB   (T*TOPK x IMED floats)
  char* ws = (char*)d_ws;
  int* counts     = (int*)(ws);
  int* tok_list   = (int*)(ws + 256);
  int* hslot_list = (int*)(ws + 256 + 524288);
  float* cw_list  = (float*)(ws + 256 + 2 * 524288);
  float* h_buf    = (float*)(ws + 256 + 3 * 524288);

  hipMemsetAsync(counts, 0, 256, stream);
  hipMemsetAsync(out, 0, (size_t)T_TOK * HID * sizeof(float), stream);

  routing_kernel<<<T_TOK, 64, 0, stream>>>(x, gate_w, counts, tok_list, hslot_list, cw_list);

  gemm1_kernel<<<dim3(IMED / BN, T_TOK / BM, EXP), 256, 0, stream>>>(
      x, qw1, qz1, sc1, counts, tok_list, hslot_list, cw_list, h_buf);

  gemm2_kernel<<<dim3(HID / BN, T_TOK / BM, EXP), 256, 0, stream>>>(
      h_buf, qw2, qz2, sc2, counts, tok_list, hslot_list, out);
}

// Round 2
// 422.188 us; speedup vs baseline: 3.8359x; 3.8359x over previous
//
#include <hip/hip_runtime.h>
#include <hip/hip_bf16.h>

#define T_TOK 2048
#define HID   1024
#define EXP   64
#define TOPK  8
#define IMED  512

typedef __bf16 bf16x8 __attribute__((ext_vector_type(8)));
typedef float f32x4 __attribute__((ext_vector_type(4)));
typedef unsigned short ushortx8 __attribute__((ext_vector_type(8)));

__constant__ int kShifts[8] = {0, 16, 4, 20, 8, 24, 12, 28};

__device__ __forceinline__ void async16(const void* g, void* l) {
  __builtin_amdgcn_global_load_lds((const __attribute__((address_space(1))) void*)g,
                                   (__attribute__((address_space(3))) void*)l, 16, 0, 0);
}

// round-to-nearest-even f32 -> bf16 bits
__device__ __forceinline__ unsigned short f2bf(float f) {
  unsigned u = __builtin_bit_cast(unsigned, f);
  unsigned r = (u + 0x7fffu + ((u >> 16) & 1u)) >> 16;
  return (unsigned short)r;
}

// ---------------- Routing (unchanged, correct) ----------------
__global__ __launch_bounds__(64) void routing_kernel(
    const float* __restrict__ x, const float* __restrict__ gate_w,
    int* __restrict__ counts, int* __restrict__ tok_list,
    int* __restrict__ hslot_list, float* __restrict__ cw_list) {
  const int t = blockIdx.x;
  const int e = threadIdx.x;

  const float4* xv = reinterpret_cast<const float4*>(x + (size_t)t * HID);
  const float4* gv = reinterpret_cast<const float4*>(gate_w + (size_t)e * HID);
  float acc = 0.f;
#pragma unroll 8
  for (int i = 0; i < HID / 4; ++i) {
    float4 a = xv[i], b = gv[i];
    acc = fmaf(a.x, b.x, acc);
    acc = fmaf(a.y, b.y, acc);
    acc = fmaf(a.z, b.z, acc);
    acc = fmaf(a.w, b.w, acc);
  }

  float m = acc;
  for (int off = 32; off; off >>= 1) m = fmaxf(m, __shfl_xor(m, off));
  float p = expf(acc - m);
  float s = p;
  for (int off = 32; off; off >>= 1) s += __shfl_xor(s, off);
  float prob = p / s;

  float pcur = prob;
  float myv = 0.f;
  int myi = -1;
  float tsum = 0.f;
  for (int k = 0; k < TOPK; ++k) {
    float v = pcur;
    int idx = e;
    for (int off = 32; off; off >>= 1) {
      float ov = __shfl_xor(v, off);
      int oi = __shfl_xor(idx, off);
      if (ov > v || (ov == v && oi < idx)) { v = ov; idx = oi; }
    }
    tsum += v;
    if (e == k) { myv = v; myi = idx; }
    if (e == idx) pcur = -1.f;
  }

  if (e < TOPK) {
    float cw = myv / tsum;
    int ex = myi;
    int slot = atomicAdd(&counts[ex], 1);
    tok_list[ex * T_TOK + slot] = t;
    hslot_list[ex * T_TOK + slot] = t * TOPK + e;
    cw_list[ex * T_TOK + slot] = cw;
  }
}

// ---------------- x fp32 -> bf16 ----------------
__global__ __launch_bounds__(256) void xcast_kernel(const float* __restrict__ x,
                                                    unsigned short* __restrict__ xbf) {
  const int idx = (blockIdx.x * 256 + threadIdx.x) * 8;
  float4 a = *reinterpret_cast<const float4*>(x + idx);
  float4 b = *reinterpret_cast<const float4*>(x + idx + 4);
  ushortx8 o;
  o[0] = f2bf(a.x); o[1] = f2bf(a.y); o[2] = f2bf(a.z); o[3] = f2bf(a.w);
  o[4] = f2bf(b.x); o[5] = f2bf(b.y); o[6] = f2bf(b.z); o[7] = f2bf(b.w);
  *reinterpret_cast<ushortx8*>(xbf + idx) = o;
}

// ---------------- AWQ dequant -> bf16, transposed to [n][k] (k contiguous) ----------------
// qw: (K, C) int32; out: (C*8, K) bf16. Group size 128 along k.
__global__ __launch_bounds__(256) void dequant_kernel(
    const int* __restrict__ qw, const int* __restrict__ qz,
    const float* __restrict__ sc, unsigned short* __restrict__ outw,
    int K, int C) {
  __shared__ unsigned short tile[128][72];  // [n_local][k_local], stride 144B (16B-aligned, bank-spread)
  const int kk = threadIdx.x & 63;
  const int cc4 = threadIdx.x >> 6;  // 0..3
  const int k = blockIdx.y * 64 + kk;
  const int c0 = blockIdx.x * 16 + cc4 * 4;
  const int g = k >> 7;
  const int N = C * 8;

  int4 q4 = *reinterpret_cast<const int4*>(qw + (size_t)k * C + c0);
  int4 z4 = *reinterpret_cast<const int4*>(qz + (size_t)g * C + c0);
  const float* sp = sc + (size_t)g * N + (size_t)c0 * 8;
  const int qs[4] = {q4.x, q4.y, q4.z, q4.w};
  const int zs[4] = {z4.x, z4.y, z4.z, z4.w};
#pragma unroll
  for (int it = 0; it < 4; ++it) {
    const unsigned q = (unsigned)qs[it];
    const unsigned z = (unsigned)zs[it];
    float4 s0 = *reinterpret_cast<const float4*>(sp + it * 8);
    float4 s1 = *reinterpret_cast<const float4*>(sp + it * 8 + 4);
    float sv[8] = {s0.x, s0.y, s0.z, s0.w, s1.x, s1.y, s1.z, s1.w};
#pragma unroll
    for (int j = 0; j < 8; ++j) {
      const int sh = kShifts[j];
      const float val = (float)((int)((q >> sh) & 15u) - (int)((z >> sh) & 15u));
      tile[(cc4 * 4 + it) * 8 + j][kk] = f2bf(val * sv[j]);
    }
  }
  __syncthreads();
  const size_t kbase = (size_t)blockIdx.y * 64;
#pragma unroll
  for (int it = 0; it < 4; ++it) {
    const int slot = threadIdx.x + 256 * it;
    const int row = slot >> 3, seg = slot & 7;
    const int n = blockIdx.x * 128 + row;
    *reinterpret_cast<ushortx8*>(outw + (size_t)n * K + kbase + seg * 8) =
        *reinterpret_cast<const ushortx8*>(&tile[row][seg * 8]);
  }
}

// ---------------- MFMA GEMM1: h[hslot, i] = silu(x . w1^T) * cw ----------------
// A = xbf gathered rows [128 x 32k], B = dqw1 rows (n = e*512 + ntile*128 + ..) [128 x 32k]
__global__ __launch_bounds__(256) void mfma_gemm1(
    const unsigned short* __restrict__ xbf, const unsigned short* __restrict__ dqw1,
    const int* __restrict__ counts, const int* __restrict__ tok_list,
    const int* __restrict__ hslot_list, const float* __restrict__ cw_list,
    unsigned short* __restrict__ h_buf) {
  const int e = blockIdx.z;
  const int n_e = counts[e];
  const int t0 = blockIdx.y * 128;
  if (t0 >= n_e) return;
  const int ntile = blockIdx.x;  // 0..3
  const int tid = threadIdx.x;
  const int wave = tid >> 6, lane = tid & 63;
  const int wm = wave & 1, wn = wave >> 1;

  __shared__ unsigned short As[128 * 32];  // [m][k], row = 64B
  __shared__ unsigned short Bs[128 * 32];  // [n][k]

  const int rsub = lane >> 2;   // 0..15
  const int csub = lane & 3;    // 16B chunk
  const int ra0 = t0 + wave * 32 + rsub;
  const int ra1 = ra0 + 16;
  const int ta0 = tok_list[e * T_TOK + min(ra0, n_e - 1)];
  const int ta1 = tok_list[e * T_TOK + min(ra1, n_e - 1)];
  const char* ga0 = (const char*)(xbf + (size_t)ta0 * HID) + csub * 16;
  const char* ga1 = (const char*)(xbf + (size_t)ta1 * HID) + csub * 16;
  const int nb = e * IMED + ntile * 128 + wave * 32 + rsub;
  const char* gb0 = (const char*)(dqw1 + (size_t)nb * HID) + csub * 16;
  const char* gb1 = gb0 + 16 * HID * 2;
  char* la0 = (char*)As + wave * 2048;
  char* la1 = la0 + 1024;
  char* lb0 = (char*)Bs + wave * 2048;
  char* lb1 = lb0 + 1024;

  f32x4 acc[4][4];
#pragma unroll
  for (int i = 0; i < 4; ++i)
#pragma unroll
    for (int j = 0; j < 4; ++j) acc[i][j] = (f32x4){0.f, 0.f, 0.f, 0.f};

  const int fr = lane & 15, fq = lane >> 4;
  for (int k0 = 0; k0 < HID; k0 += 32) {
    async16(ga0, la0); async16(ga1, la1);
    async16(gb0, lb0); async16(gb1, lb1);
    ga0 += 64; ga1 += 64; gb0 += 64; gb1 += 64;
    __syncthreads();
    bf16x8 af[4], bfr[4];
#pragma unroll
    for (int i = 0; i < 4; ++i)
      af[i] = *reinterpret_cast<const bf16x8*>(As + (wm * 64 + i * 16 + fr) * 32 + fq * 8);
#pragma unroll
    for (int j = 0; j < 4; ++j)
      bfr[j] = *reinterpret_cast<const bf16x8*>(Bs + (wn * 64 + j * 16 + fr) * 32 + fq * 8);
#pragma unroll
    for (int i = 0; i < 4; ++i)
#pragma unroll
      for (int j = 0; j < 4; ++j)
        acc[i][j] = __builtin_amdgcn_mfma_f32_16x16x32_bf16(af[i], bfr[j], acc[i][j], 0, 0, 0);
    __syncthreads();
  }

  // epilogue: C/D map col = lane&15, row = (lane>>4)*4 + reg
#pragma unroll
  for (int i = 0; i < 4; ++i) {
#pragma unroll
    for (int r = 0; r < 4; ++r) {
      const int grow = t0 + wm * 64 + i * 16 + fq * 4 + r;
      if (grow < n_e) {
        const float cw = cw_list[e * T_TOK + grow];
        const int hs = hslot_list[e * T_TOK + grow];
        unsigned short* dst = h_buf + (size_t)hs * IMED + ntile * 128 + wn * 64 + fr;
#pragma unroll
        for (int j = 0; j < 4; ++j) {
          const float v = acc[i][j][r];
          dst[j * 16] = f2bf((v / (1.f + __expf(-v))) * cw);
        }
      }
    }
  }
}

// ---------------- MFMA GEMM2: out[t, n] += h[hslot,:] . w2^T ----------------
__global__ __launch_bounds__(256) void mfma_gemm2(
    const unsigned short* __restrict__ h_buf, const unsigned short* __restrict__ dqw2,
    const int* __restrict__ counts, const int* __restrict__ tok_list,
    const int* __restrict__ hslot_list, float* __restrict__ out) {
  const int e = blockIdx.z;
  const int n_e = counts[e];
  const int t0 = blockIdx.y * 128;
  if (t0 >= n_e) return;
  const int ntile = blockIdx.x;  // 0..7
  const int tid = threadIdx.x;
  const int wave = tid >> 6, lane = tid & 63;
  const int wm = wave & 1, wn = wave >> 1;

  __shared__ unsigned short As[128 * 32];
  __shared__ unsigned short Bs[128 * 32];

  const int rsub = lane >> 2;
  const int csub = lane & 3;
  const int ra0 = t0 + wave * 32 + rsub;
  const int ra1 = ra0 + 16;
  const int ha0 = hslot_list[e * T_TOK + min(ra0, n_e - 1)];
  const int ha1 = hslot_list[e * T_TOK + min(ra1, n_e - 1)];
  const char* ga0 = (const char*)(h_buf + (size_t)ha0 * IMED) + csub * 16;
  const char* ga1 = (const char*)(h_buf + (size_t)ha1 * IMED) + csub * 16;
  const int nb = e * HID + ntile * 128 + wave * 32 + rsub;
  const char* gb0 = (const char*)(dqw2 + (size_t)nb * IMED) + csub * 16;
  const char* gb1 = gb0 + 16 * IMED * 2;
  char* la0 = (char*)As + wave * 2048;
  char* la1 = la0 + 1024;
  char* lb0 = (char*)Bs + wave * 2048;
  char* lb1 = lb0 + 1024;

  f32x4 acc[4][4];
#pragma unroll
  for (int i = 0; i < 4; ++i)
#pragma unroll
    for (int j = 0; j < 4; ++j) acc[i][j] = (f32x4){0.f, 0.f, 0.f, 0.f};

  const int fr = lane & 15, fq = lane >> 4;
  for (int k0 = 0; k0 < IMED; k0 += 32) {
    async16(ga0, la0); async16(ga1, la1);
    async16(gb0, lb0); async16(gb1, lb1);
    ga0 += 64; ga1 += 64; gb0 += 64; gb1 += 64;
    __syncthreads();
    bf16x8 af[4], bfr[4];
#pragma unroll
    for (int i = 0; i < 4; ++i)
      af[i] = *reinterpret_cast<const bf16x8*>(As + (wm * 64 + i * 16 + fr) * 32 + fq * 8);
#pragma unroll
    for (int j = 0; j < 4; ++j)
      bfr[j] = *reinterpret_cast<const bf16x8*>(Bs + (wn * 64 + j * 16 + fr) * 32 + fq * 8);
#pragma unroll
    for (int i = 0; i < 4; ++i)
#pragma unroll
      for (int j = 0; j < 4; ++j)
        acc[i][j] = __builtin_amdgcn_mfma_f32_16x16x32_bf16(af[i], bfr[j], acc[i][j], 0, 0, 0);
    __syncthreads();
  }

#pragma unroll
  for (int i = 0; i < 4; ++i) {
#pragma unroll
    for (int r = 0; r < 4; ++r) {
      const int grow = t0 + wm * 64 + i * 16 + fq * 4 + r;
      if (grow < n_e) {
        const int t = tok_list[e * T_TOK + grow];
        float* dst = out + (size_t)t * HID + ntile * 128 + wn * 64 + fr;
#pragma unroll
        for (int j = 0; j < 4; ++j) atomicAdd(dst + j * 16, acc[i][j][r]);
      }
    }
  }
}

extern "C" void kernel_launch(void* const* d_in, const int* in_sizes, int n_in,
                              void* d_out, int out_size, void* d_ws, size_t ws_size,
                              hipStream_t stream) {
  const float* x      = (const float*)d_in[0];
  const float* gate_w = (const float*)d_in[1];
  const int*   qw1    = (const int*)d_in[2];
  const int*   qz1    = (const int*)d_in[3];
  const float* sc1    = (const float*)d_in[4];
  const int*   qw2    = (const int*)d_in[5];
  const int*   qz2    = (const int*)d_in[6];
  const float* sc2    = (const float*)d_in[7];
  float* out = (float*)d_out;

  // workspace layout
  char* ws = (char*)d_ws;
  int* counts              = (int*)(ws);                       // 256 B
  int* tok_list            = (int*)(ws + 256);                 // 512 KB
  int* hslot_list          = (int*)(ws + 524544);              // 512 KB
  float* cw_list           = (float*)(ws + 1048832);           // 512 KB
  unsigned short* h_buf    = (unsigned short*)(ws + 1573120);  // 16.8 MB (16384 x 512 bf16)
  unsigned short* xbf      = (unsigned short*)(ws + 18350336); // 4.2 MB (2048 x 1024 bf16)
  unsigned short* dqw1     = (unsigned short*)(ws + 22544640); // 67 MB (32768 x 1024 bf16)
  unsigned short* dqw2     = (unsigned short*)(ws + 89653504); // 67 MB (65536 x 512 bf16)

  hipMemsetAsync(counts, 0, 256, stream);
  hipMemsetAsync(out, 0, (size_t)T_TOK * HID * sizeof(float), stream);

  routing_kernel<<<T_TOK, 64, 0, stream>>>(x, gate_w, counts, tok_list, hslot_list, cw_list);
  xcast_kernel<<<(T_TOK * HID) / (256 * 8), 256, 0, stream>>>(x, xbf);
  dequant_kernel<<<dim3(4096 / 16, 1024 / 64), 256, 0, stream>>>(qw1, qz1, sc1, dqw1, HID, 4096);
  dequant_kernel<<<dim3(8192 / 16, 512 / 64), 256, 0, stream>>>(qw2, qz2, sc2, dqw2, IMED, 8192);

  mfma_gemm1<<<dim3(IMED / 128, T_TOK / 128, EXP), 256, 0, stream>>>(
      xbf, dqw1, counts, tok_list, hslot_list, cw_list, h_buf);
  mfma_gemm2<<<dim3(HID / 128, T_TOK / 128, EXP), 256, 0, stream>>>(
      h_buf, dqw2, counts, tok_list, hslot_list, out);
}

// Round 3
// 387.773 us; speedup vs baseline: 4.1763x; 1.0887x over previous
//
#include <hip/hip_runtime.h>
#include <hip/hip_bf16.h>

#define T_TOK 2048
#define HID   1024
#define EXP   64
#define TOPK  8
#define IMED  512

typedef __bf16 bf16x8 __attribute__((ext_vector_type(8)));
typedef float f32x4 __attribute__((ext_vector_type(4)));
typedef unsigned short ushortx8 __attribute__((ext_vector_type(8)));

__constant__ int kShifts[8] = {0, 16, 4, 20, 8, 24, 12, 28};

__device__ __forceinline__ void async16(const void* g, void* l) {
  __builtin_amdgcn_global_load_lds((const __attribute__((address_space(1))) void*)g,
                                   (__attribute__((address_space(3))) void*)l, 16, 0, 0);
}

// round-to-nearest-even f32 -> bf16 bits
__device__ __forceinline__ unsigned short f2bf(float f) {
  unsigned u = __builtin_bit_cast(unsigned, f);
  unsigned r = (u + 0x7fffu + ((u >> 16) & 1u)) >> 16;
  return (unsigned short)r;
}

__device__ __forceinline__ float bf2f(unsigned short b) {
  unsigned u = ((unsigned)b) << 16;
  return __builtin_bit_cast(float, u);
}

// ---------------- Routing + x->bf16 cast fused ----------------
__global__ __launch_bounds__(64) void routing_kernel(
    const float* __restrict__ x, const float* __restrict__ gate_w,
    int* __restrict__ counts, int* __restrict__ tok_list,
    int* __restrict__ hslot_list, float* __restrict__ cw_list,
    unsigned short* __restrict__ xbf) {
  const int t = blockIdx.x;
  const int e = threadIdx.x;

  const float4* xv = reinterpret_cast<const float4*>(x + (size_t)t * HID);
  const float4* gv = reinterpret_cast<const float4*>(gate_w + (size_t)e * HID);
  float acc = 0.f;
#pragma unroll 8
  for (int i = 0; i < HID / 4; ++i) {
    float4 a = xv[i], b = gv[i];
    acc = fmaf(a.x, b.x, acc);
    acc = fmaf(a.y, b.y, acc);
    acc = fmaf(a.z, b.z, acc);
    acc = fmaf(a.w, b.w, acc);
  }

  // bf16 cast of this token's row: lane e handles 16 consecutive elements
  {
    const float* src = x + (size_t)t * HID + e * 16;
#pragma unroll
    for (int h = 0; h < 2; ++h) {
      float4 a = *reinterpret_cast<const float4*>(src + h * 8);
      float4 b = *reinterpret_cast<const float4*>(src + h * 8 + 4);
      ushortx8 o;
      o[0] = f2bf(a.x); o[1] = f2bf(a.y); o[2] = f2bf(a.z); o[3] = f2bf(a.w);
      o[4] = f2bf(b.x); o[5] = f2bf(b.y); o[6] = f2bf(b.z); o[7] = f2bf(b.w);
      *reinterpret_cast<ushortx8*>(xbf + (size_t)t * HID + e * 16 + h * 8) = o;
    }
  }

  float m = acc;
  for (int off = 32; off; off >>= 1) m = fmaxf(m, __shfl_xor(m, off));
  float p = expf(acc - m);
  float s = p;
  for (int off = 32; off; off >>= 1) s += __shfl_xor(s, off);
  float prob = p / s;

  float pcur = prob;
  float myv = 0.f;
  int myi = -1;
  float tsum = 0.f;
  for (int k = 0; k < TOPK; ++k) {
    float v = pcur;
    int idx = e;
    for (int off = 32; off; off >>= 1) {
      float ov = __shfl_xor(v, off);
      int oi = __shfl_xor(idx, off);
      if (ov > v || (ov == v && oi < idx)) { v = ov; idx = oi; }
    }
    tsum += v;
    if (e == k) { myv = v; myi = idx; }
    if (e == idx) pcur = -1.f;
  }

  if (e < TOPK) {
    float cw = myv / tsum;
    int ex = myi;
    int slot = atomicAdd(&counts[ex], 1);
    tok_list[ex * T_TOK + slot] = t;
    hslot_list[ex * T_TOK + slot] = t * TOPK + e;
    cw_list[ex * T_TOK + slot] = cw;
  }
}

// ---------------- AWQ dequant -> bf16, transposed to [n][k] (k contiguous) ----------------
__global__ __launch_bounds__(256) void dequant_kernel(
    const int* __restrict__ qw, const int* __restrict__ qz,
    const float* __restrict__ sc, unsigned short* __restrict__ outw,
    int K, int C) {
  __shared__ unsigned short tile[128][72];
  const int kk = threadIdx.x & 63;
  const int cc4 = threadIdx.x >> 6;  // 0..3
  const int k = blockIdx.y * 64 + kk;
  const int c0 = blockIdx.x * 16 + cc4 * 4;
  const int g = k >> 7;
  const int N = C * 8;

  int4 q4 = *reinterpret_cast<const int4*>(qw + (size_t)k * C + c0);
  int4 z4 = *reinterpret_cast<const int4*>(qz + (size_t)g * C + c0);
  const float* sp = sc + (size_t)g * N + (size_t)c0 * 8;
  const int qs[4] = {q4.x, q4.y, q4.z, q4.w};
  const int zs[4] = {z4.x, z4.y, z4.z, z4.w};
#pragma unroll
  for (int it = 0; it < 4; ++it) {
    const unsigned q = (unsigned)qs[it];
    const unsigned z = (unsigned)zs[it];
    float4 s0 = *reinterpret_cast<const float4*>(sp + it * 8);
    float4 s1 = *reinterpret_cast<const float4*>(sp + it * 8 + 4);
    float sv[8] = {s0.x, s0.y, s0.z, s0.w, s1.x, s1.y, s1.z, s1.w};
#pragma unroll
    for (int j = 0; j < 8; ++j) {
      const int sh = kShifts[j];
      const float val = (float)((int)((q >> sh) & 15u) - (int)((z >> sh) & 15u));
      tile[(cc4 * 4 + it) * 8 + j][kk] = f2bf(val * sv[j]);
    }
  }
  __syncthreads();
  const size_t kbase = (size_t)blockIdx.y * 64;
#pragma unroll
  for (int it = 0; it < 4; ++it) {
    const int slot = threadIdx.x + 256 * it;
    const int row = slot >> 3, seg = slot & 7;
    const int n = blockIdx.x * 128 + row;
    *reinterpret_cast<ushortx8*>(outw + (size_t)n * K + kbase + seg * 8) =
        *reinterpret_cast<const ushortx8*>(&tile[row][seg * 8]);
  }
}

// ---------------- MFMA GEMM1 (double-buffered): h[hslot, i] = silu(x . w1^T) * cw ----------------
__global__ __launch_bounds__(256) void mfma_gemm1(
    const unsigned short* __restrict__ xbf, const unsigned short* __restrict__ dqw1,
    const int* __restrict__ counts, const int* __restrict__ tok_list,
    const int* __restrict__ hslot_list, const float* __restrict__ cw_list,
    unsigned short* __restrict__ h_buf) {
  const int e = blockIdx.z;
  const int n_e = counts[e];
  const int t0 = blockIdx.y * 128;
  if (t0 >= n_e) return;
  const int ntile = blockIdx.x;  // 0..3
  const int tid = threadIdx.x;
  const int wave = tid >> 6, lane = tid & 63;
  const int wm = wave & 1, wn = wave >> 1;

  __shared__ unsigned short As[2][128 * 32];  // [buf][m][k], 8KB per buf
  __shared__ unsigned short Bs[2][128 * 32];

  const int rsub = lane >> 2;
  const int csub = lane & 3;
  const int ra0 = t0 + wave * 32 + rsub;
  const int ra1 = ra0 + 16;
  const int ta0 = tok_list[e * T_TOK + min(ra0, n_e - 1)];
  const int ta1 = tok_list[e * T_TOK + min(ra1, n_e - 1)];
  const char* ga0 = (const char*)(xbf + (size_t)ta0 * HID) + csub * 16;
  const char* ga1 = (const char*)(xbf + (size_t)ta1 * HID) + csub * 16;
  const int nb = e * IMED + ntile * 128 + wave * 32 + rsub;
  const char* gb0 = (const char*)(dqw1 + (size_t)nb * HID) + csub * 16;
  const char* gb1 = gb0 + 16 * HID * 2;

  f32x4 acc[4][4];
#pragma unroll
  for (int i = 0; i < 4; ++i)
#pragma unroll
    for (int j = 0; j < 4; ++j) acc[i][j] = (f32x4){0.f, 0.f, 0.f, 0.f};

  const int fr = lane & 15, fq = lane >> 4;

  auto stage = [&](int b) {
    char* la = (char*)&As[b][0] + wave * 2048;
    char* lb = (char*)&Bs[b][0] + wave * 2048;
    async16(ga0, la);
    async16(ga1, la + 1024);
    async16(gb0, lb);
    async16(gb1, lb + 1024);
    ga0 += 64; ga1 += 64; gb0 += 64; gb1 += 64;
  };

  stage(0);
  int p = 0;
  for (int k0 = 0; k0 < HID; k0 += 32) {
    __syncthreads();  // drains async into buf p
    if (k0 + 32 < HID) stage(p ^ 1);  // prefetch next tile during compute
    bf16x8 af[4], bfr[4];
#pragma unroll
    for (int i = 0; i < 4; ++i)
      af[i] = *reinterpret_cast<const bf16x8*>(&As[p][(wm * 64 + i * 16 + fr) * 32 + fq * 8]);
#pragma unroll
    for (int j = 0; j < 4; ++j)
      bfr[j] = *reinterpret_cast<const bf16x8*>(&Bs[p][(wn * 64 + j * 16 + fr) * 32 + fq * 8]);
#pragma unroll
    for (int i = 0; i < 4; ++i)
#pragma unroll
      for (int j = 0; j < 4; ++j)
        acc[i][j] = __builtin_amdgcn_mfma_f32_16x16x32_bf16(af[i], bfr[j], acc[i][j], 0, 0, 0);
    p ^= 1;
  }

  // epilogue: C/D map col = lane&15, row = (lane>>4)*4 + reg
#pragma unroll
  for (int i = 0; i < 4; ++i) {
#pragma unroll
    for (int r = 0; r < 4; ++r) {
      const int grow = t0 + wm * 64 + i * 16 + fq * 4 + r;
      if (grow < n_e) {
        const float cw = cw_list[e * T_TOK + grow];
        const int hs = hslot_list[e * T_TOK + grow];
        unsigned short* dst = h_buf + (size_t)hs * IMED + ntile * 128 + wn * 64 + fr;
#pragma unroll
        for (int j = 0; j < 4; ++j) {
          const float v = acc[i][j][r];
          dst[j * 16] = f2bf((v / (1.f + __expf(-v))) * cw);
        }
      }
    }
  }
}

// ---------------- MFMA GEMM2 (double-buffered): p_buf[hslot, n] = h[hslot,:] . w2^T ----------------
__global__ __launch_bounds__(256) void mfma_gemm2(
    const unsigned short* __restrict__ h_buf, const unsigned short* __restrict__ dqw2,
    const int* __restrict__ counts, const int* __restrict__ hslot_list,
    unsigned short* __restrict__ p_buf) {
  const int e = blockIdx.z;
  const int n_e = counts[e];
  const int t0 = blockIdx.y * 128;
  if (t0 >= n_e) return;
  const int ntile = blockIdx.x;  // 0..7
  const int tid = threadIdx.x;
  const int wave = tid >> 6, lane = tid & 63;
  const int wm = wave & 1, wn = wave >> 1;

  __shared__ unsigned short As[2][128 * 32];
  __shared__ unsigned short Bs[2][128 * 32];

  const int rsub = lane >> 2;
  const int csub = lane & 3;
  const int ra0 = t0 + wave * 32 + rsub;
  const int ra1 = ra0 + 16;
  const int ha0 = hslot_list[e * T_TOK + min(ra0, n_e - 1)];
  const int ha1 = hslot_list[e * T_TOK + min(ra1, n_e - 1)];
  const char* ga0 = (const char*)(h_buf + (size_t)ha0 * IMED) + csub * 16;
  const char* ga1 = (const char*)(h_buf + (size_t)ha1 * IMED) + csub * 16;
  const int nb = e * HID + ntile * 128 + wave * 32 + rsub;
  const char* gb0 = (const char*)(dqw2 + (size_t)nb * IMED) + csub * 16;
  const char* gb1 = gb0 + 16 * IMED * 2;

  f32x4 acc[4][4];
#pragma unroll
  for (int i = 0; i < 4; ++i)
#pragma unroll
    for (int j = 0; j < 4; ++j) acc[i][j] = (f32x4){0.f, 0.f, 0.f, 0.f};

  const int fr = lane & 15, fq = lane >> 4;

  auto stage = [&](int b) {
    char* la = (char*)&As[b][0] + wave * 2048;
    char* lb = (char*)&Bs[b][0] + wave * 2048;
    async16(ga0, la);
    async16(ga1, la + 1024);
    async16(gb0, lb);
    async16(gb1, lb + 1024);
    ga0 += 64; ga1 += 64; gb0 += 64; gb1 += 64;
  };

  stage(0);
  int p = 0;
  for (int k0 = 0; k0 < IMED; k0 += 32) {
    __syncthreads();
    if (k0 + 32 < IMED) stage(p ^ 1);
    bf16x8 af[4], bfr[4];
#pragma unroll
    for (int i = 0; i < 4; ++i)
      af[i] = *reinterpret_cast<const bf16x8*>(&As[p][(wm * 64 + i * 16 + fr) * 32 + fq * 8]);
#pragma unroll
    for (int j = 0; j < 4; ++j)
      bfr[j] = *reinterpret_cast<const bf16x8*>(&Bs[p][(wn * 64 + j * 16 + fr) * 32 + fq * 8]);
#pragma unroll
    for (int i = 0; i < 4; ++i)
#pragma unroll
      for (int j = 0; j < 4; ++j)
        acc[i][j] = __builtin_amdgcn_mfma_f32_16x16x32_bf16(af[i], bfr[j], acc[i][j], 0, 0, 0);
    p ^= 1;
  }

  // epilogue: plain bf16 partial stores (no atomics); every (hslot, col) written once
#pragma unroll
  for (int i = 0; i < 4; ++i) {
#pragma unroll
    for (int r = 0; r < 4; ++r) {
      const int grow = t0 + wm * 64 + i * 16 + fq * 4 + r;
      if (grow < n_e) {
        const int hs = hslot_list[e * T_TOK + grow];
        unsigned short* dst = p_buf + (size_t)hs * HID + ntile * 128 + wn * 64 + fr;
#pragma unroll
        for (int j = 0; j < 4; ++j) dst[j * 16] = f2bf(acc[i][j][r]);
      }
    }
  }
}

// ---------------- Reduce 8 partials per token -> out (fp32) ----------------
__global__ __launch_bounds__(256) void reduce_kernel(const unsigned short* __restrict__ p_buf,
                                                     float* __restrict__ out) {
  const int idx = blockIdx.x * 256 + threadIdx.x;  // T_TOK*HID/8 total
  const int t = idx >> 7;          // 128 groups of 8 cols per token
  const int c0 = (idx & 127) * 8;
  float s[8] = {0.f, 0.f, 0.f, 0.f, 0.f, 0.f, 0.f, 0.f};
#pragma unroll
  for (int k = 0; k < TOPK; ++k) {
    ushortx8 v = *reinterpret_cast<const ushortx8*>(p_buf + ((size_t)t * TOPK + k) * HID + c0);
#pragma unroll
    for (int j = 0; j < 8; ++j) s[j] += bf2f(v[j]);
  }
  float* dst = out + (size_t)t * HID + c0;
  *reinterpret_cast<float4*>(dst) = make_float4(s[0], s[1], s[2], s[3]);
  *reinterpret_cast<float4*>(dst + 4) = make_float4(s[4], s[5], s[6], s[7]);
}

extern "C" void kernel_launch(void* const* d_in, const int* in_sizes, int n_in,
                              void* d_out, int out_size, void* d_ws, size_t ws_size,
                              hipStream_t stream) {
  const float* x      = (const float*)d_in[0];
  const float* gate_w = (const float*)d_in[1];
  const int*   qw1    = (const int*)d_in[2];
  const int*   qz1    = (const int*)d_in[3];
  const float* sc1    = (const float*)d_in[4];
  const int*   qw2    = (const int*)d_in[5];
  const int*   qz2    = (const int*)d_in[6];
  const float* sc2    = (const float*)d_in[7];
  float* out = (float*)d_out;

  // workspace layout (p_buf aliases dqw1, which is dead after gemm1)
  char* ws = (char*)d_ws;
  int* counts              = (int*)(ws);                       // 256 B
  int* tok_list            = (int*)(ws + 256);                 // 512 KB
  int* hslot_list          = (int*)(ws + 524544);              // 512 KB
  float* cw_list           = (float*)(ws + 1048832);           // 512 KB
  unsigned short* h_buf    = (unsigned short*)(ws + 1573120);  // 16.8 MB
  unsigned short* xbf      = (unsigned short*)(ws + 18350336); // 4.2 MB
  unsigned short* dqw1     = (unsigned short*)(ws + 22544640); // 67 MB
  unsigned short* dqw2     = (unsigned short*)(ws + 89653504); // 67 MB
  unsigned short* p_buf    = (unsigned short*)(ws + 22544640); // 33.6 MB (aliases dqw1)

  hipMemsetAsync(counts, 0, 256, stream);

  routing_kernel<<<T_TOK, 64, 0, stream>>>(x, gate_w, counts, tok_list, hslot_list, cw_list, xbf);
  dequant_kernel<<<dim3(4096 / 16, 1024 / 64), 256, 0, stream>>>(qw1, qz1, sc1, dqw1, HID, 4096);
  dequant_kernel<<<dim3(8192 / 16, 512 / 64), 256, 0, stream>>>(qw2, qz2, sc2, dqw2, IMED, 8192);

  mfma_gemm1<<<dim3(IMED / 128, T_TOK / 128, EXP), 256, 0, stream>>>(
      xbf, dqw1, counts, tok_list, hslot_list, cw_list, h_buf);
  mfma_gemm2<<<dim3(HID / 128, T_TOK / 128, EXP), 256, 0, stream>>>(
      h_buf, dqw2, counts, hslot_list, p_buf);
  reduce_kernel<<<(T_TOK * HID / 8) / 256, 256, 0, stream>>>(p_buf, out);
}